// Round 7
// baseline (301.678 us; speedup 1.0000x reference)
//
#include <hip/hip_runtime.h>
#include <hip/hip_bf16.h>
#include <math.h>

#define Bn 4096
#define Dd 768
#define INV_T 20.0f
#define EPSF 1e-6f
#define DG 4.8516519541e8f   // expf(20.0f): exact exp_ori diagonal

// ws layout (4-byte elements)
#define O_S      0        // 3*4096 row sums (ori_nodiag, gen, aug)
#define O_SMOA   12288    // same-masked (ori_nodiag + aug) sums
#define O_SMG    16384    // same-masked gen sums
#define O_DCO    20480
#define O_DAD    24576
#define O_LOSS   28672    // [0]=ad acc, [1]=co acc
#define O_P      28676    // uint: total pairs (= sum cnt^2)
#define O_RANK   29312    // uint[4096]
#define O_RSB    33408    // uint[4096] row slot base
#define ZERO_BYTES 131072
#define LIST_OFF   262144      // byte offset: LCAP uint4 pair entries
#define LCAP       (1u << 19)
#define NB_OFF     33554432    // byte offset: bf16 normalized rows on|gn|an

typedef __attribute__((ext_vector_type(8))) short sh8;
typedef __attribute__((ext_vector_type(4))) float f32x4;

#define AS1 __attribute__((address_space(1)))
#define AS3 __attribute__((address_space(3)))

static __device__ __forceinline__ void gl_lds16(const void* g, void* l) {
    __builtin_amdgcn_global_load_lds((const AS1 void*)g, (AS3 void*)l, 16, 0, 0);
}

static __device__ __forceinline__ unsigned short f2b(float f) {
    unsigned int u = __float_as_uint(f);
    unsigned int r = (u + 0x7fffu + ((u >> 16) & 1u)) >> 16;  // RNE
    return (unsigned short)r;
}

// ---- normalize rows, write bf16 ----
__global__ void norm_kernel(const float* f0, const float* f1, const float* f2, unsigned short* nb) {
    int r = blockIdx.x, m = blockIdx.y, tid = threadIdx.x;
    const float* src = (m == 0 ? f0 : (m == 1 ? f1 : f2)) + (size_t)r * Dd;
    float x0 = src[tid], x1 = src[tid + 256], x2 = src[tid + 512];
    float v = x0 * x0 + x1 * x1 + x2 * x2;
    #pragma unroll
    for (int off = 1; off < 64; off <<= 1) v += __shfl_xor(v, off);
    __shared__ float wr[4];
    if ((tid & 63) == 0) wr[tid >> 6] = v;
    __syncthreads();
    float inv = rsqrtf(wr[0] + wr[1] + wr[2] + wr[3]);
    unsigned short* dst = nb + ((size_t)m * Bn + r) * Dd;
    dst[tid] = f2b(x0 * inv);
    dst[tid + 256] = f2b(x1 * inv);
    dst[tid + 512] = f2b(x2 * inv);
}

// ---- single-block class sort: LDS histogram + scan + rank/slot scatter ----
__launch_bounds__(1024)
__global__ void sort_kernel(const int* tg, unsigned int* I) {
    __shared__ unsigned int h[128], sc[128], pb[128], cur[128];
    int tid = threadIdx.x;
    if (tid < 128) { h[tid] = 0; cur[tid] = 0; }
    __syncthreads();
    for (int e = tid; e < Bn; e += 1024) atomicAdd(&h[tg[e]], 1u);
    __syncthreads();
    if (tid < 128) { sc[tid] = h[tid]; pb[tid] = h[tid] * h[tid]; }
    __syncthreads();
    for (int s = 1; s < 128; s <<= 1) {
        unsigned int a = 0, b = 0;
        if (tid < 128 && tid >= s) { a = sc[tid - s]; b = pb[tid - s]; }
        __syncthreads();
        if (tid < 128) { sc[tid] += a; pb[tid] += b; }
        __syncthreads();
    }
    if (tid == 127) I[O_P] = pb[127];
    for (int e = tid; e < Bn; e += 1024) {
        int c = tg[e];
        unsigned int r = atomicAdd(&cur[c], 1u);
        unsigned int n = h[c];
        I[O_RANK + e] = r;
        I[O_RSB + e] = (pb[c] - n * n) + r * n;
    }
}

// ---- fused 3-operand GEMM + exp row-sums + masked sums + pair extraction.
// One block computes the 128x128 tile of on@on^T, on@gn^T, on@an^T (A staged
// once, 48 MFMA per barrier pair vs 16 unfused -- R6 was barrier-bound at
// MfmaUtil 20%). Pair slots deterministic (RSB[i]+rank[j]) -> fire-and-forget
// uint4 stores; NO returning atomics (R4/R5 lesson: they serialize the grid).
// LDS swizzle pos = seg ^ ((row>>1)&3): conflict-free (R4-R6: 0 conflicts).
__launch_bounds__(256)
__global__ void gemm_rowsum(const unsigned short* nb, const int* tg, char* ws) {
    float* F = (float*)ws;
    const unsigned int* I = (const unsigned int*)ws;
    uint4* L = (uint4*)(ws + LIST_OFF);
    int m0 = blockIdx.y * 128, n0 = blockIdx.x * 128;
    int tid = threadIdx.x, lane = tid & 63, wave = tid >> 6;
    int wm = (wave >> 1) * 64, wn = (wave & 1) * 64;
    int lid = lane & 15, q = lane >> 4;
    __shared__ __align__(16) unsigned short Asm[128 * 32];
    __shared__ __align__(16) unsigned short Bsm[3][128 * 32];
    int c0 = tid, c1 = tid + 256;
    int row0 = c0 >> 2, sg0 = (c0 & 3) ^ ((row0 >> 1) & 3);
    int row1 = c1 >> 2, sg1 = (c1 & 3) ^ ((row1 >> 1) & 3);
    const unsigned short* gA0 = nb + (size_t)(m0 + row0) * Dd + sg0 * 8;
    const unsigned short* gA1 = nb + (size_t)(m0 + row1) * Dd + sg1 * 8;
    const unsigned short* gB0 = nb + (size_t)(n0 + row0) * Dd + sg0 * 8;
    const unsigned short* gB1 = nb + (size_t)(n0 + row1) * Dd + sg1 * 8;
    f32x4 acc[3][4][4] = {};
    for (int kt = 0; kt < Dd / 32; ++kt) {
        __syncthreads();
        gl_lds16(gA0 + kt * 32, &Asm[c0 * 8]);
        gl_lds16(gA1 + kt * 32, &Asm[c1 * 8]);
        #pragma unroll
        for (int z = 0; z < 3; ++z) {
            gl_lds16(gB0 + (size_t)z * Bn * Dd + kt * 32, &Bsm[z][c0 * 8]);
            gl_lds16(gB1 + (size_t)z * Bn * Dd + kt * 32, &Bsm[z][c1 * 8]);
        }
        __syncthreads();
        sh8 af[4];
        #pragma unroll
        for (int i = 0; i < 4; ++i) {
            int r = wm + i * 16 + lid;
            af[i] = *(const sh8*)&Asm[r * 32 + ((q ^ ((r >> 1) & 3)) * 8)];
        }
        #pragma unroll
        for (int z = 0; z < 3; ++z) {
            sh8 bf[4];
            #pragma unroll
            for (int j = 0; j < 4; ++j) {
                int r = wn + j * 16 + lid;
                bf[j] = *(const sh8*)&Bsm[z][r * 32 + ((q ^ ((r >> 1) & 3)) * 8)];
            }
            #pragma unroll
            for (int i = 0; i < 4; ++i)
                #pragma unroll
                for (int j = 0; j < 4; ++j)
                    acc[z][i][j] = __builtin_amdgcn_mfma_f32_16x16x32_bf16(af[i], bf[j], acc[z][i][j], 0, 0, 0);
        }
    }
    // ---- epilogue: 3 row-sums, 2 masked sums, deterministic uint4 pair stores ----
    int tcol[4]; unsigned int rkc[4];
    #pragma unroll
    for (int j = 0; j < 4; ++j) {
        int gc = n0 + wn + j * 16 + lid;
        tcol[j] = tg[gc];
        rkc[j] = I[O_RANK + gc];
    }
    #pragma unroll
    for (int i = 0; i < 4; ++i)
        #pragma unroll
        for (int reg = 0; reg < 4; ++reg) {
            int grow = m0 + wm + i * 16 + q * 4 + reg;
            int trow = tg[grow];
            unsigned int rsb = I[O_RSB + grow];
            float rs0 = 0.f, rs1 = 0.f, rs2 = 0.f, msoa = 0.f, msg = 0.f;
            #pragma unroll
            for (int j = 0; j < 4; ++j) {
                int gcol = n0 + wn + j * 16 + lid;
                float x0 = acc[0][i][j][reg] * INV_T;
                float x1 = acc[1][i][j][reg] * INV_T;
                float x2 = acc[2][i][j][reg] * INV_T;
                float e0 = __expf(x0), e1 = __expf(x1), e2 = __expf(x2);
                if (gcol == grow) e0 = 0.f;    // exclude ori diagonal (both sums)
                rs0 += e0; rs1 += e1; rs2 += e2;
                if (tcol[j] == trow) {
                    msoa += e0 + e2; msg += e1;
                    unsigned int slot = rsb + rkc[j];
                    if (slot < LCAP)
                        L[slot] = make_uint4((unsigned)grow, __float_as_uint(x0),
                                             __float_as_uint(x1), __float_as_uint(x2));
                }
            }
            #pragma unroll
            for (int off = 1; off < 16; off <<= 1) {
                rs0 += __shfl_xor(rs0, off);
                rs1 += __shfl_xor(rs1, off);
                rs2 += __shfl_xor(rs2, off);
                msoa += __shfl_xor(msoa, off);
                msg += __shfl_xor(msg, off);
            }
            if (lid == 0) {
                atomicAdd(&F[O_S + grow], rs0);
                atomicAdd(&F[O_S + Bn + grow], rs1);
                atomicAdd(&F[O_S + 2 * Bn + grow], rs2);
                atomicAdd(&F[O_SMOA + grow], msoa);
                atomicAdd(&F[O_SMG + grow], msg);
            }
        }
}

__global__ void denom_kernel(float* F) {
    int i = blockIdx.x * 256 + threadIdx.x;
    if (i < Bn) {
        float son = F[O_S + i], sgen = F[O_S + Bn + i], saug = F[O_S + 2 * Bn + i];
        F[O_DCO + i] = (son + saug - F[O_SMOA + i]) + sgen + EPSF;
        F[O_DAD + i] = (sgen - F[O_SMG + i]) + saug + son + DG + EPSF;
    }
}

// ---- flat loss pass over the extracted pair list ----
__launch_bounds__(256)
__global__ void loss_kernel(char* ws) {
    float* F = (float*)ws;
    const unsigned int* I = (const unsigned int*)ws;
    const uint4* L = (const uint4*)(ws + LIST_OFF);
    unsigned int n = I[O_P]; if (n > LCAP) n = LCAP;
    float a0 = 0.f, a1 = 0.f;
    unsigned int stride = gridDim.x * 256;
    for (unsigned int idx = blockIdx.x * 256 + threadIdx.x; idx < n; idx += stride) {
        uint4 en = L[idx];
        int i = (int)en.x;
        float dco = F[O_DCO + i], dad = F[O_DAD + i];
        float eo = __expf(__uint_as_float(en.y));
        float eg = __expf(__uint_as_float(en.z));
        float ea = __expf(__uint_as_float(en.w));
        a0 += -__logf(eg / (eg + dad) + EPSF);
        a1 += -__logf(eo / (eo + dco) + EPSF) - __logf(ea / (ea + dco) + EPSF);
    }
    #pragma unroll
    for (int off = 1; off < 64; off <<= 1) { a0 += __shfl_xor(a0, off); a1 += __shfl_xor(a1, off); }
    __shared__ float r0[4], r1[4];
    int tid = threadIdx.x;
    if ((tid & 63) == 0) { r0[tid >> 6] = a0; r1[tid >> 6] = a1; }
    __syncthreads();
    if (tid == 0) {
        atomicAdd(&F[O_LOSS + 0], r0[0] + r0[1] + r0[2] + r0[3]);
        atomicAdd(&F[O_LOSS + 1], r1[0] + r1[1] + r1[2] + r1[3]);
    }
}

__global__ void final_kernel(const float* F, float* out) {
    out[0] = F[O_LOSS + 0] * (1.0f / Bn);  // ad_loss
    out[1] = F[O_LOSS + 1] * (1.0f / Bn);  // co_loss
}

extern "C" void kernel_launch(void* const* d_in, const int* in_sizes, int n_in,
                              void* d_out, int out_size, void* d_ws, size_t ws_size,
                              hipStream_t stream) {
    const float* f0 = (const float*)d_in[0];
    const float* f1 = (const float*)d_in[1];
    const float* f2 = (const float*)d_in[2];
    const int* tg = (const int*)d_in[3];
    char* ws = (char*)d_ws;
    float* F = (float*)d_ws;
    unsigned int* I = (unsigned int*)d_ws;
    unsigned short* nb = (unsigned short*)(ws + NB_OFF);
    float* out = (float*)d_out;

    hipMemsetAsync(d_ws, 0, ZERO_BYTES, stream);
    norm_kernel<<<dim3(Bn, 3), 256, 0, stream>>>(f0, f1, f2, nb);
    sort_kernel<<<1, 1024, 0, stream>>>(tg, I);
    gemm_rowsum<<<dim3(32, 32), 256, 0, stream>>>(nb, tg, ws);
    denom_kernel<<<Bn / 256, 256, 0, stream>>>(F);
    loss_kernel<<<256, 256, 0, stream>>>(ws);
    final_kernel<<<1, 1, 0, stream>>>(F, out);
}

// Round 8
// 276.611 us; speedup vs baseline: 1.0906x; 1.0906x over previous
//
#include <hip/hip_runtime.h>
#include <hip/hip_bf16.h>
#include <math.h>

#define Bn 4096
#define Dd 768
#define INV_T 20.0f
#define EPSF 1e-6f
#define DG 4.8516519541e8f   // expf(20.0f): exact exp_ori diagonal

// ws layout (4-byte elements)
#define O_S      0        // 3*4096 row sums (ori_nodiag, gen, aug)
#define O_SMOA   12288    // same-masked (ori_nodiag + aug) sums
#define O_SMG    16384    // same-masked gen sums
#define O_DCO    20480
#define O_DAD    24576
#define O_LOSS   28672    // [0]=ad acc, [1]=co acc
#define O_P      28676    // uint: total pairs (= sum cnt^2)
#define O_RANK   29312    // uint[4096]
#define O_RSB    33408    // uint[4096] row slot base
#define ZERO_BYTES 131072
#define LIST_OFF   262144      // byte offset: LCAP uint4 pair entries {row,x0,x1,x2}
#define LCAP       (1u << 19)
#define NB_OFF     33554432    // byte offset: bf16 normalized rows on|gn|an

typedef __attribute__((ext_vector_type(8))) short sh8;
typedef __attribute__((ext_vector_type(4))) float f32x4;

#define AS1 __attribute__((address_space(1)))
#define AS3 __attribute__((address_space(3)))

static __device__ __forceinline__ void gl_lds16(const void* g, void* l) {
    __builtin_amdgcn_global_load_lds((const AS1 void*)g, (AS3 void*)l, 16, 0, 0);
}

static __device__ __forceinline__ unsigned short f2b(float f) {
    unsigned int u = __float_as_uint(f);
    unsigned int r = (u + 0x7fffu + ((u >> 16) & 1u)) >> 16;  // RNE
    return (unsigned short)r;
}

// ---- normalize rows, write bf16 ----
__global__ void norm_kernel(const float* f0, const float* f1, const float* f2, unsigned short* nb) {
    int r = blockIdx.x, m = blockIdx.y, tid = threadIdx.x;
    const float* src = (m == 0 ? f0 : (m == 1 ? f1 : f2)) + (size_t)r * Dd;
    float x0 = src[tid], x1 = src[tid + 256], x2 = src[tid + 512];
    float v = x0 * x0 + x1 * x1 + x2 * x2;
    #pragma unroll
    for (int off = 1; off < 64; off <<= 1) v += __shfl_xor(v, off);
    __shared__ float wr[4];
    if ((tid & 63) == 0) wr[tid >> 6] = v;
    __syncthreads();
    float inv = rsqrtf(wr[0] + wr[1] + wr[2] + wr[3]);
    unsigned short* dst = nb + ((size_t)m * Bn + r) * Dd;
    dst[tid] = f2b(x0 * inv);
    dst[tid + 256] = f2b(x1 * inv);
    dst[tid + 512] = f2b(x2 * inv);
}

// ---- single-block class sort: LDS histogram + scan + rank/slot scatter ----
__launch_bounds__(1024)
__global__ void sort_kernel(const int* tg, unsigned int* I) {
    __shared__ unsigned int h[128], pb[128], cur[128];
    int tid = threadIdx.x;
    if (tid < 128) { h[tid] = 0; cur[tid] = 0; }
    __syncthreads();
    for (int e = tid; e < Bn; e += 1024) atomicAdd(&h[tg[e]], 1u);
    __syncthreads();
    if (tid < 128) pb[tid] = h[tid] * h[tid];
    __syncthreads();
    for (int s = 1; s < 128; s <<= 1) {
        unsigned int b = 0;
        if (tid < 128 && tid >= s) b = pb[tid - s];
        __syncthreads();
        if (tid < 128) pb[tid] += b;
        __syncthreads();
    }
    if (tid == 127) I[O_P] = pb[127];
    for (int e = tid; e < Bn; e += 1024) {
        int c = tg[e];
        unsigned int r = atomicAdd(&cur[c], 1u);
        unsigned int n = h[c];
        I[O_RANK + e] = r;
        I[O_RSB + e] = (pb[c] - n * n) + r * n;
    }
}

// ---- fused GEMM + exp row-sum + masked sums + deterministic pair extraction.
// z selects B-operand (0:on 1:gn 2:an); A is always on. BK=64: 32 MFMA per
// barrier pair (R6 at BK=32 was barrier-bound, MfmaUtil 20%). LDS 32 KB keeps
// ~5 blocks/CU (R7 lesson: acc[3][..] fusion -> 372 unified regs -> 1 wave/SIMD
// -> 212us. Keep acc at 48 regs/thread.)
// Swizzle pos = seg ^ (row&7): 16-lane b128 phase covers 8 distinct 4-bank
// groups, 2 rows/pos = free 2-way.
// Pair slots deterministic (RSB[i]+rank[j]) -> fire-and-forget stores, NO
// returning atomics (R4: per-lane cursor 4.3ms; R5: per-wave cursor +130us).
__launch_bounds__(256)
__global__ void gemm_rowsum(const unsigned short* nb, const int* tg, char* ws) {
    float* F = (float*)ws;
    const unsigned int* I = (const unsigned int*)ws;
    int z = blockIdx.z;
    const unsigned short* Ag = nb;
    const unsigned short* Bg = nb + (size_t)z * Bn * Dd;
    int m0 = blockIdx.y * 128, n0 = blockIdx.x * 128;
    int tid = threadIdx.x, lane = tid & 63, wave = tid >> 6;
    int wm = (wave >> 1) * 64, wn = (wave & 1) * 64;
    int lid = lane & 15, q = lane >> 4;
    __shared__ __align__(16) unsigned short Asm[128 * 64];
    __shared__ __align__(16) unsigned short Bsm[128 * 64];
    // staging: seg index c (0..1023): row = c>>3, pos = c&7, global seg = pos^(row&7)
    int srow[4], sgseg[4];
    #pragma unroll
    for (int s = 0; s < 4; ++s) {
        int c = tid + s * 256;
        srow[s] = c >> 3;
        sgseg[s] = (c & 7) ^ (srow[s] & 7);
    }
    f32x4 acc[4][4] = {};
    for (int kt = 0; kt < Dd / 64; ++kt) {
        __syncthreads();
        #pragma unroll
        for (int s = 0; s < 4; ++s) {
            int c = tid + s * 256;
            gl_lds16(Ag + (size_t)(m0 + srow[s]) * Dd + kt * 64 + sgseg[s] * 8, &Asm[c * 8]);
            gl_lds16(Bg + (size_t)(n0 + srow[s]) * Dd + kt * 64 + sgseg[s] * 8, &Bsm[c * 8]);
        }
        __syncthreads();
        #pragma unroll
        for (int ko = 0; ko < 2; ++ko) {
            sh8 af[4], bf[4];
            #pragma unroll
            for (int i = 0; i < 4; ++i) {
                int r = wm + i * 16 + lid;
                af[i] = *(const sh8*)&Asm[r * 64 + (((ko * 4 + q) ^ (r & 7)) * 8)];
            }
            #pragma unroll
            for (int j = 0; j < 4; ++j) {
                int r = wn + j * 16 + lid;
                bf[j] = *(const sh8*)&Bsm[r * 64 + (((ko * 4 + q) ^ (r & 7)) * 8)];
            }
            #pragma unroll
            for (int i = 0; i < 4; ++i)
                #pragma unroll
                for (int j = 0; j < 4; ++j)
                    acc[i][j] = __builtin_amdgcn_mfma_f32_16x16x32_bf16(af[i], bf[j], acc[i][j], 0, 0, 0);
        }
    }
    // ---- epilogue: row sum, masked sum, pair-list word stores ----
    int tcol[4]; unsigned int rkc[4];
    #pragma unroll
    for (int j = 0; j < 4; ++j) {
        int gc = n0 + wn + j * 16 + lid;
        tcol[j] = tg[gc];
        rkc[j] = I[O_RANK + gc];
    }
    int smoff = (z == 1) ? O_SMG : O_SMOA;
    unsigned int* Lw = (unsigned int*)(ws + LIST_OFF);
    #pragma unroll
    for (int i = 0; i < 4; ++i)
        #pragma unroll
        for (int reg = 0; reg < 4; ++reg) {
            int grow = m0 + wm + i * 16 + q * 4 + reg;
            int trow = tg[grow];
            unsigned int rsb = I[O_RSB + grow];
            float rs = 0.f, ms = 0.f;
            #pragma unroll
            for (int j = 0; j < 4; ++j) {
                int gcol = n0 + wn + j * 16 + lid;
                float x = acc[i][j][reg] * INV_T;
                float e = __expf(x);
                if (z == 0 && gcol == grow) e = 0.f;
                rs += e;
                if (tcol[j] == trow) {
                    ms += e;
                    unsigned int slot = rsb + rkc[j];
                    if (slot < LCAP) {
                        if (z == 0) {
                            Lw[slot * 4 + 0] = (unsigned)grow;
                            Lw[slot * 4 + 1] = __float_as_uint(x);
                        } else {
                            Lw[slot * 4 + 1 + z] = __float_as_uint(x);
                        }
                    }
                }
            }
            #pragma unroll
            for (int off = 1; off < 16; off <<= 1) {
                rs += __shfl_xor(rs, off);
                ms += __shfl_xor(ms, off);
            }
            if (lid == 0) {
                atomicAdd(&F[O_S + z * Bn + grow], rs);
                atomicAdd(&F[smoff + grow], ms);
            }
        }
}

__global__ void denom_kernel(float* F) {
    int i = blockIdx.x * 256 + threadIdx.x;
    if (i < Bn) {
        float son = F[O_S + i], sgen = F[O_S + Bn + i], saug = F[O_S + 2 * Bn + i];
        F[O_DCO + i] = (son + saug - F[O_SMOA + i]) + sgen + EPSF;
        F[O_DAD + i] = (sgen - F[O_SMG + i]) + saug + son + DG + EPSF;
    }
}

// ---- flat loss pass over the extracted pair list ----
__launch_bounds__(256)
__global__ void loss_kernel(char* ws) {
    float* F = (float*)ws;
    const unsigned int* I = (const unsigned int*)ws;
    const uint4* L = (const uint4*)(ws + LIST_OFF);
    unsigned int n = I[O_P]; if (n > LCAP) n = LCAP;
    float a0 = 0.f, a1 = 0.f;
    unsigned int stride = gridDim.x * 256;
    for (unsigned int idx = blockIdx.x * 256 + threadIdx.x; idx < n; idx += stride) {
        uint4 en = L[idx];
        int i = (int)en.x;
        float dco = F[O_DCO + i], dad = F[O_DAD + i];
        float eo = __expf(__uint_as_float(en.y));
        float eg = __expf(__uint_as_float(en.z));
        float ea = __expf(__uint_as_float(en.w));
        a0 += -__logf(eg / (eg + dad) + EPSF);
        a1 += -__logf(eo / (eo + dco) + EPSF) - __logf(ea / (ea + dco) + EPSF);
    }
    #pragma unroll
    for (int off = 1; off < 64; off <<= 1) { a0 += __shfl_xor(a0, off); a1 += __shfl_xor(a1, off); }
    __shared__ float r0[4], r1[4];
    int tid = threadIdx.x;
    if ((tid & 63) == 0) { r0[tid >> 6] = a0; r1[tid >> 6] = a1; }
    __syncthreads();
    if (tid == 0) {
        atomicAdd(&F[O_LOSS + 0], r0[0] + r0[1] + r0[2] + r0[3]);
        atomicAdd(&F[O_LOSS + 1], r1[0] + r1[1] + r1[2] + r1[3]);
    }
}

__global__ void final_kernel(const float* F, float* out) {
    out[0] = F[O_LOSS + 0] * (1.0f / Bn);  // ad_loss
    out[1] = F[O_LOSS + 1] * (1.0f / Bn);  // co_loss
}

extern "C" void kernel_launch(void* const* d_in, const int* in_sizes, int n_in,
                              void* d_out, int out_size, void* d_ws, size_t ws_size,
                              hipStream_t stream) {
    const float* f0 = (const float*)d_in[0];
    const float* f1 = (const float*)d_in[1];
    const float* f2 = (const float*)d_in[2];
    const int* tg = (const int*)d_in[3];
    char* ws = (char*)d_ws;
    float* F = (float*)d_ws;
    unsigned int* I = (unsigned int*)d_ws;
    unsigned short* nb = (unsigned short*)(ws + NB_OFF);
    float* out = (float*)d_out;

    hipMemsetAsync(d_ws, 0, ZERO_BYTES, stream);
    norm_kernel<<<dim3(Bn, 3), 256, 0, stream>>>(f0, f1, f2, nb);
    sort_kernel<<<1, 1024, 0, stream>>>(tg, I);
    gemm_rowsum<<<dim3(32, 32, 3), 256, 0, stream>>>(nb, tg, ws);
    denom_kernel<<<Bn / 256, 256, 0, stream>>>(F);
    loss_kernel<<<256, 256, 0, stream>>>(ws);
    final_kernel<<<1, 1, 0, stream>>>(F, out);
}

// Round 9
// 234.887 us; speedup vs baseline: 1.2844x; 1.1776x over previous
//
#include <hip/hip_runtime.h>
#include <hip/hip_bf16.h>
#include <math.h>

#define Bn 4096
#define Dd 768
#define INV_T 20.0f
#define EPSF 1e-6f
#define DG 4.8516519541e8f   // expf(20.0f): exact exp_ori diagonal

// ws layout (4-byte elements)
#define O_S      0        // 3*4096 row sums (ori_nodiag, gen, aug)
#define O_SMOA   12288    // same-masked (ori_nodiag + aug) sums
#define O_SMG    16384    // same-masked gen sums
#define ZERO_F   20480    // floats to zero (covers all atomic sums)
#define O_P      20480    // uint: total pairs (= sum cnt^2)
#define O_RM     20608    // uint2[4096]: {tg | rank<<8, rowSlotBase}
#define LIST_OFF   262144      // byte offset: LCAP uint4 pair entries {row,x0,x1,x2}
#define LCAP       (1u << 19)
#define NB_OFF     33554432    // byte offset: bf16 normalized rows on|gn|an

typedef __attribute__((ext_vector_type(8))) short sh8;
typedef __attribute__((ext_vector_type(4))) float f32x4;

#define AS1 __attribute__((address_space(1)))
#define AS3 __attribute__((address_space(3)))

static __device__ __forceinline__ void gl_lds16(const void* g, void* l) {
    __builtin_amdgcn_global_load_lds((const AS1 void*)g, (AS3 void*)l, 16, 0, 0);
}

static __device__ __forceinline__ unsigned short f2b(float f) {
    unsigned int u = __float_as_uint(f);
    unsigned int r = (u + 0x7fffu + ((u >> 16) & 1u)) >> 16;  // RNE
    return (unsigned short)r;
}

// ---- normalize rows, write bf16 ----
__global__ void norm_kernel(const float* f0, const float* f1, const float* f2, unsigned short* nb) {
    int r = blockIdx.x, m = blockIdx.y, tid = threadIdx.x;
    const float* src = (m == 0 ? f0 : (m == 1 ? f1 : f2)) + (size_t)r * Dd;
    float x0 = src[tid], x1 = src[tid + 256], x2 = src[tid + 512];
    float v = x0 * x0 + x1 * x1 + x2 * x2;
    #pragma unroll
    for (int off = 1; off < 64; off <<= 1) v += __shfl_xor(v, off);
    __shared__ float wr[4];
    if ((tid & 63) == 0) wr[tid >> 6] = v;
    __syncthreads();
    float inv = rsqrtf(wr[0] + wr[1] + wr[2] + wr[3]);
    unsigned short* dst = nb + ((size_t)m * Bn + r) * Dd;
    dst[tid] = f2b(x0 * inv);
    dst[tid + 256] = f2b(x1 * inv);
    dst[tid + 512] = f2b(x2 * inv);
}

// ---- single-block: zero accumulators + class sort (hist/scan/rank+slot) ----
__launch_bounds__(1024)
__global__ void sort_kernel(const int* tg, unsigned int* I, float* out) {
    float* F = (float*)I;
    __shared__ unsigned int h[128], pb[128], cur[128];
    int tid = threadIdx.x;
    for (int e = tid; e < ZERO_F; e += 1024) F[e] = 0.f;
    if (tid == 0) { out[0] = 0.f; out[1] = 0.f; }
    if (tid < 128) { h[tid] = 0; cur[tid] = 0; }
    __syncthreads();
    for (int e = tid; e < Bn; e += 1024) atomicAdd(&h[tg[e]], 1u);
    __syncthreads();
    if (tid < 128) pb[tid] = h[tid] * h[tid];
    __syncthreads();
    for (int s = 1; s < 128; s <<= 1) {
        unsigned int b = 0;
        if (tid < 128 && tid >= s) b = pb[tid - s];
        __syncthreads();
        if (tid < 128) pb[tid] += b;
        __syncthreads();
    }
    if (tid == 127) I[O_P] = pb[127];
    uint2* RM = (uint2*)(I + O_RM);
    for (int e = tid; e < Bn; e += 1024) {
        int c = tg[e];
        unsigned int r = atomicAdd(&cur[c], 1u);
        unsigned int n = h[c];
        RM[e] = make_uint2((unsigned)c | (r << 8), (pb[c] - n * n) + r * n);
    }
}

// ---- fused GEMM + exp row-sum + masked sums + deterministic pair extraction.
// z selects B-operand (0:on 1:gn 2:an); A is always on. BK=32 (R8: BK=64
// dropped occupancy 31->21% and regressed; keep R6's 159us config exactly).
// LDS swizzle pos = seg ^ ((row>>1)&3): conflict-free (R4-R8: 0 conflicts).
// Pair slots deterministic (rsb[i]+rank[j]) -> fire-and-forget stores, NO
// returning atomics (R4: per-lane cursor 4.3ms; R5: per-wave cursor +130us).
__launch_bounds__(256)
__global__ void gemm_rowsum(const unsigned short* nb, char* ws) {
    float* F = (float*)ws;
    const unsigned int* I = (const unsigned int*)ws;
    const uint2* RM = (const uint2*)(I + O_RM);
    int z = blockIdx.z;
    const unsigned short* Ag = nb;
    const unsigned short* Bg = nb + (size_t)z * Bn * Dd;
    int m0 = blockIdx.y * 128, n0 = blockIdx.x * 128;
    int tid = threadIdx.x, lane = tid & 63, wave = tid >> 6;
    int wm = (wave >> 1) * 64, wn = (wave & 1) * 64;
    int lid = lane & 15, q = lane >> 4;
    __shared__ __align__(16) unsigned short Asm[128 * 32];
    __shared__ __align__(16) unsigned short Bsm[128 * 32];
    int c0 = tid, c1 = tid + 256;
    int row0 = c0 >> 2, sg0 = (c0 & 3) ^ ((row0 >> 1) & 3);
    int row1 = c1 >> 2, sg1 = (c1 & 3) ^ ((row1 >> 1) & 3);
    const unsigned short* gA0 = Ag + (size_t)(m0 + row0) * Dd + sg0 * 8;
    const unsigned short* gA1 = Ag + (size_t)(m0 + row1) * Dd + sg1 * 8;
    const unsigned short* gB0 = Bg + (size_t)(n0 + row0) * Dd + sg0 * 8;
    const unsigned short* gB1 = Bg + (size_t)(n0 + row1) * Dd + sg1 * 8;
    unsigned short* lA0 = &Asm[c0 * 8];
    unsigned short* lA1 = &Asm[c1 * 8];
    unsigned short* lB0 = &Bsm[c0 * 8];
    unsigned short* lB1 = &Bsm[c1 * 8];
    f32x4 acc[4][4] = {};
    for (int kt = 0; kt < Dd / 32; ++kt) {
        __syncthreads();
        gl_lds16(gA0 + kt * 32, lA0);
        gl_lds16(gA1 + kt * 32, lA1);
        gl_lds16(gB0 + kt * 32, lB0);
        gl_lds16(gB1 + kt * 32, lB1);
        __syncthreads();
        sh8 af[4], bf[4];
        #pragma unroll
        for (int i = 0; i < 4; ++i) {
            int r = wm + i * 16 + lid;
            af[i] = *(const sh8*)&Asm[r * 32 + ((q ^ ((r >> 1) & 3)) * 8)];
        }
        #pragma unroll
        for (int j = 0; j < 4; ++j) {
            int r = wn + j * 16 + lid;
            bf[j] = *(const sh8*)&Bsm[r * 32 + ((q ^ ((r >> 1) & 3)) * 8)];
        }
        #pragma unroll
        for (int i = 0; i < 4; ++i)
            #pragma unroll
            for (int j = 0; j < 4; ++j)
                acc[i][j] = __builtin_amdgcn_mfma_f32_16x16x32_bf16(af[i], bf[j], acc[i][j], 0, 0, 0);
    }
    // ---- epilogue: row sum, masked sum, pair-list word stores ----
    unsigned int rmc[4];
    #pragma unroll
    for (int j = 0; j < 4; ++j) rmc[j] = RM[n0 + wn + j * 16 + lid].x;
    int smoff = (z == 1) ? O_SMG : O_SMOA;
    unsigned int* Lw = (unsigned int*)(ws + LIST_OFF);
    #pragma unroll
    for (int i = 0; i < 4; ++i)
        #pragma unroll
        for (int reg = 0; reg < 4; ++reg) {
            int grow = m0 + wm + i * 16 + q * 4 + reg;
            uint2 rm = RM[grow];
            unsigned int trow = rm.x & 255u, rsb = rm.y;
            float rs = 0.f, ms = 0.f;
            #pragma unroll
            for (int j = 0; j < 4; ++j) {
                int gcol = n0 + wn + j * 16 + lid;
                float x = acc[i][j][reg] * INV_T;
                float e = __expf(x);
                if (z == 0 && gcol == grow) e = 0.f;
                rs += e;
                if ((rmc[j] & 255u) == trow) {
                    ms += e;
                    unsigned int slot = rsb + (rmc[j] >> 8);
                    if (slot < LCAP) {
                        if (z == 0) {
                            Lw[slot * 4 + 0] = (unsigned)grow;
                            Lw[slot * 4 + 1] = __float_as_uint(x);
                        } else {
                            Lw[slot * 4 + 1 + z] = __float_as_uint(x);
                        }
                    }
                }
            }
            #pragma unroll
            for (int off = 1; off < 16; off <<= 1) {
                rs += __shfl_xor(rs, off);
                ms += __shfl_xor(ms, off);
            }
            if (lid == 0) {
                atomicAdd(&F[O_S + z * Bn + grow], rs);
                atomicAdd(&F[smoff + grow], ms);
            }
        }
}

// ---- flat loss pass: inline denominators, scaled atomic into d_out ----
__launch_bounds__(256)
__global__ void loss_kernel(char* ws, float* out) {
    float* F = (float*)ws;
    const unsigned int* I = (const unsigned int*)ws;
    const uint4* L = (const uint4*)(ws + LIST_OFF);
    unsigned int n = I[O_P]; if (n > LCAP) n = LCAP;
    float a0 = 0.f, a1 = 0.f;
    unsigned int stride = gridDim.x * 256;
    for (unsigned int idx = blockIdx.x * 256 + threadIdx.x; idx < n; idx += stride) {
        uint4 en = L[idx];
        int i = (int)en.x;
        float son = F[O_S + i], sgen = F[O_S + Bn + i], saug = F[O_S + 2 * Bn + i];
        float dco = (son + saug - F[O_SMOA + i]) + sgen + EPSF;
        float dad = (sgen - F[O_SMG + i]) + saug + son + DG + EPSF;
        float eo = __expf(__uint_as_float(en.y));
        float eg = __expf(__uint_as_float(en.z));
        float ea = __expf(__uint_as_float(en.w));
        a0 += -__logf(eg / (eg + dad) + EPSF);
        a1 += -__logf(eo / (eo + dco) + EPSF) - __logf(ea / (ea + dco) + EPSF);
    }
    #pragma unroll
    for (int off = 1; off < 64; off <<= 1) { a0 += __shfl_xor(a0, off); a1 += __shfl_xor(a1, off); }
    __shared__ float r0[4], r1[4];
    int tid = threadIdx.x;
    if ((tid & 63) == 0) { r0[tid >> 6] = a0; r1[tid >> 6] = a1; }
    __syncthreads();
    if (tid == 0) {
        atomicAdd(&out[0], (r0[0] + r0[1] + r0[2] + r0[3]) * (1.0f / Bn));  // ad_loss
        atomicAdd(&out[1], (r1[0] + r1[1] + r1[2] + r1[3]) * (1.0f / Bn));  // co_loss
    }
}

extern "C" void kernel_launch(void* const* d_in, const int* in_sizes, int n_in,
                              void* d_out, int out_size, void* d_ws, size_t ws_size,
                              hipStream_t stream) {
    const float* f0 = (const float*)d_in[0];
    const float* f1 = (const float*)d_in[1];
    const float* f2 = (const float*)d_in[2];
    const int* tg = (const int*)d_in[3];
    char* ws = (char*)d_ws;
    unsigned int* I = (unsigned int*)d_ws;
    unsigned short* nb = (unsigned short*)(ws + NB_OFF);
    float* out = (float*)d_out;

    norm_kernel<<<dim3(Bn, 3), 256, 0, stream>>>(f0, f1, f2, nb);
    sort_kernel<<<1, 1024, 0, stream>>>(tg, I, out);
    gemm_rowsum<<<dim3(32, 32, 3), 256, 0, stream>>>(nb, ws);
    loss_kernel<<<256, 256, 0, stream>>>(ws, out);
}